// Round 10
// baseline (469.339 us; speedup 1.0000x reference)
//
#include <hip/hip_runtime.h>
#include <math.h>

#define ALPHA 0.99f
typedef float f4 __attribute__((ext_vector_type(4)));

constexpr int NROWS = 16;
constexpr int NS    = 1 << 21;      // samples per row
constexpr int BT    = 256;          // threads per block (4 waves)
constexpr int R     = 128;          // samples per thread
constexpr int TILE  = BT * R;       // 32768 samples per block
constexpr int BPR   = NS / TILE;    // 64 blocks per row
constexpr int NBLK  = NROWS * BPR;  // 1024 blocks = 4/CU (LDS-pinned), co-resident
constexpr int LCH   = 19;           // f4-chunks parked in LDS per thread (76 samples)
                                    // remaining 13 chunks (52 samples) in 26 named regs

constexpr double dpow(double a, long n){ double r=1.0; while(n>0){ if(n&1) r*=a; a*=a; n>>=1; } return r; }
constexpr double s2c_calc(){ double s=0,p=1; for(int t=1;t<=R;++t){ p*=0.99*0.99; s+=p; } return s; }
constexpr double csum_calc(){ double s=0,pw=1; const double f=dpow(0.99,2L*R); for(int i=0;i<BT;++i){ s+=pw; pw*=f; } return s; }

constexpr float W1  = (float)dpow(0.99, 128);   // scan hop weights alpha^(128*2^k)
constexpr float W2  = (float)dpow(0.99, 256);
constexpr float W4  = (float)dpow(0.99, 512);
constexpr float W8  = (float)dpow(0.99, 1024);
constexpr float W16 = (float)dpow(0.99, 2048);
constexpr float W32 = (float)dpow(0.99, 4096);
constexpr float ASPAN  = (float)dpow(0.99, 8192);   // 64 lanes * 128 samples (~1.6e-36, normal)
constexpr float S2C    = (float)s2c_calc();
constexpr float CCONST = (float)(s2c_calc()*csum_calc());
constexpr float L2A128 = -1.85594487f;              // 128*log2(0.99)

// RNE float->bf16 pack of two floats into one u32 (lo = a, hi = b)
static __device__ __forceinline__ unsigned pack2(float a, float b){
    unsigned ua = __builtin_bit_cast(unsigned, a);
    unsigned ub = __builtin_bit_cast(unsigned, b);
    ua += 0x7FFFu + ((ua >> 16) & 1u);
    ub += 0x7FFFu + ((ub >> 16) & 1u);
    return (ua >> 16) | (ub & 0xFFFF0000u);
}
static __device__ __forceinline__ float unlo(unsigned u){ return __builtin_bit_cast(float, u << 16); }
static __device__ __forceinline__ float unhi(unsigned u){ return __builtin_bit_cast(float, u & 0xFFFF0000u); }

// One fused kernel. KEY CHANGE vs R5-R9: the x-park is split LDS(76)/regs(52
// samples), and the ~39 KB LDS block PHYSICALLY caps occupancy at 4 blocks/CU
// (16 waves/CU = 4 waves/EU). The register allocator's occupancy heuristic —
// which at 512B LDS targeted 8 waves/EU and spilled every park variant to
// scratch (VGPR_Count=64, +190..360 MB scratch traffic in R5/R7/R8/R9) — can
// no longer pick >4 waves/EU, so its VGPR budget is 128 by construction.
__global__ __launch_bounds__(BT, 4) void k_fused(const float* __restrict__ x,
                                                 int* __restrict__ cnt,     // [NROWS]
                                                 float* __restrict__ stats, // [NBLK*3]
                                                 float* __restrict__ out) {
    const int b   = blockIdx.x;
    const int row = b / BPR, jb = b % BPR;
    const int tid = threadIdx.x;
    const int lane = tid & 63, wid = tid >> 6;

    __shared__ unsigned pk_lds[2*LCH*BT];   // 38912 B: bf16-packed park, [k*BT+tid] conflict-free
    __shared__ float waveZ[4], pa[4], pb[4];
    __shared__ float sZb, sgain;

    const size_t base = (size_t)row*NS + (size_t)jb*TILE + (size_t)tid*R;
    const f4* xv = reinterpret_cast<const f4*>(x + base);

    const bool rowstart = (jb==0) && (tid==0);
    float xm1 = rowstart ? 0.0f : x[base-1];

    float z=0.f, p=1.f, S0=0.f, S1=0.f;
    float mprev = ALPHA*xm1;

#define STEP(xx, FIRST) { float m_ = ALPHA*(xx); float b_ = (FIRST) ? (xx) : (m_-mprev); \
    z = fmaf(ALPHA, z, b_); p *= ALPHA; S0 = fmaf(z,z,S0); S1 = fmaf(z,p,S1); mprev = m_; }

    // ---- phase 1a: chunks 0..18 -> LDS park (in IIR order) ----
#pragma unroll
    for (int c=0;c<LCH;++c){
        f4 v = xv[c];
        STEP(v.x, rowstart && c==0) STEP(v.y,false) STEP(v.z,false) STEP(v.w,false)
        pk_lds[(2*c  )*BT + tid] = pack2(v.x, v.y);
        pk_lds[(2*c+1)*BT + tid] = pack2(v.z, v.w);
    }

    // ---- phase 1b: chunks 19..31 -> 26 named scalar regs (in IIR order) ----
    unsigned q0,q1,q2,q3,q4,q5,q6,q7,q8,q9,q10,q11,q12,q13,
             q14,q15,q16,q17,q18,q19,q20,q21,q22,q23,q24,q25;
#define RC(c,A,B){ f4 v = xv[c]; \
    STEP(v.x,false) STEP(v.y,false) STEP(v.z,false) STEP(v.w,false) \
    A = pack2(v.x,v.y); B = pack2(v.z,v.w); }
    RC(19,q0,q1)  RC(20,q2,q3)  RC(21,q4,q5)  RC(22,q6,q7)
    RC(23,q8,q9)  RC(24,q10,q11) RC(25,q12,q13) RC(26,q14,q15)
    RC(27,q16,q17) RC(28,q18,q19) RC(29,q20,q21) RC(30,q22,q23)
    RC(31,q24,q25)
#undef RC
#undef STEP

    // ---- weighted inclusive scan of thread carries z (hop weight alpha^128) ----
    float incl = z;
    { float t1=__shfl_up(incl,1);  if(lane>=1)  incl=fmaf(W1 ,t1,incl); }
    { float t1=__shfl_up(incl,2);  if(lane>=2)  incl=fmaf(W2 ,t1,incl); }
    { float t1=__shfl_up(incl,4);  if(lane>=4)  incl=fmaf(W4 ,t1,incl); }
    { float t1=__shfl_up(incl,8);  if(lane>=8)  incl=fmaf(W8 ,t1,incl); }
    { float t1=__shfl_up(incl,16); if(lane>=16) incl=fmaf(W16,t1,incl); }
    { float t1=__shfl_up(incl,32); if(lane>=32) incl=fmaf(W32,t1,incl); }

    if (lane==63) waveZ[wid]=incl;
    __syncthreads();

    float P=0.f;
    for (int u=0;u<wid;++u) P=fmaf(ASPAN,P,waveZ[u]);   // state entering this wave

    float excl=__shfl_up(incl,1); if(lane==0) excl=0.f;
    float wl = exp2f((float)lane * L2A128);             // alpha^(128*lane)
    float E  = fmaf(wl,P,excl);                         // state entering this thread

    // per-thread contribution, quadratic in block-incoming state Y
    float ai = fmaf(S2C*E,E, fmaf(2.0f*S1,E,S0));
    float Qi = exp2f((float)tid * L2A128);              // alpha^(128*tid) (underflow->0 ok)
    float bi = 2.0f*Qi*fmaf(S2C,E,S1);

    if (tid==BT-1) sZb = fmaf(ASPAN,P,incl);            // block zero-state output

    for (int d=32; d; d>>=1){ ai+=__shfl_xor(ai,d); bi+=__shfl_xor(bi,d); }
    if (lane==0){ pa[wid]=ai; pb[wid]=bi; }
    __syncthreads();

    // ---- publish stats + per-row arrive/spin barrier (R5-proven pattern) ----
    if (tid==0){
        float A = pa[0]+pa[1]+pa[2]+pa[3];
        float B = pb[0]+pb[1]+pb[2]+pb[3];
        __hip_atomic_store(&stats[b*3+0], A,   __ATOMIC_RELAXED, __HIP_MEMORY_SCOPE_AGENT);
        __hip_atomic_store(&stats[b*3+1], B,   __ATOMIC_RELAXED, __HIP_MEMORY_SCOPE_AGENT);
        __hip_atomic_store(&stats[b*3+2], sZb, __ATOMIC_RELAXED, __HIP_MEMORY_SCOPE_AGENT);
        __threadfence();
        atomicAdd(&cnt[row], 1);
        while (__hip_atomic_load(&cnt[row], __ATOMIC_ACQUIRE, __HIP_MEMORY_SCOPE_AGENT) < BPR)
            __builtin_amdgcn_s_sleep(8);
    }
    __syncthreads();

    // ---- row gain: wave 0 reduces its row's 64 block-stats (deterministic) ----
    if (tid < 64){
        const float* st = &stats[((size_t)row*BPR + lane)*3];
        float a2 = __hip_atomic_load(&st[0], __ATOMIC_RELAXED, __HIP_MEMORY_SCOPE_AGENT);
        float b2 = __hip_atomic_load(&st[1], __ATOMIC_RELAXED, __HIP_MEMORY_SCOPE_AGENT);
        float zl = __hip_atomic_load(&st[2], __ATOMIC_RELAXED, __HIP_MEMORY_SCOPE_AGENT);
        float zp = __shfl_up(zl,1); if(lane==0) zp=0.f; // Y_in(block j) = Z_{j-1}
        float s = fmaf(CCONST, zp*zp, fmaf(b2,zp,a2));
        for (int d=32; d; d>>=1) s += __shfl_xor(s,d);
        if (tid==0){
            float ms   = s * (1.0f/(float)NS);
            float lufs = -0.691f + 10.0f*log10f(ms + 1e-8f);
            float gdb  = fminf(fmaxf(-23.0f-lufs,-30.0f),30.0f);
            sgain = exp2f(gdb*0.1660964047f);           // 10^(gdb/20)
        }
    }
    __syncthreads();
    const float g = sgain;

    // ---- phase 2: unpack parked bf16 (LDS + regs), scale, NT-store out ----
    f4* ov = reinterpret_cast<f4*>(out + base);
#pragma unroll
    for (int c=0;c<LCH;++c){
        unsigned a_ = pk_lds[(2*c  )*BT + tid];
        unsigned b_ = pk_lds[(2*c+1)*BT + tid];
        f4 w;
        w.x = unlo(a_)*g; w.y = unhi(a_)*g;
        w.z = unlo(b_)*g; w.w = unhi(b_)*g;
        __builtin_nontemporal_store(w, ov + c);
    }
#define OC(c,A,B){ f4 w; \
    w.x = unlo(A)*g; w.y = unhi(A)*g; w.z = unlo(B)*g; w.w = unhi(B)*g; \
    __builtin_nontemporal_store(w, ov + (c)); }
    OC(19,q0,q1)  OC(20,q2,q3)  OC(21,q4,q5)  OC(22,q6,q7)
    OC(23,q8,q9)  OC(24,q10,q11) OC(25,q12,q13) OC(26,q14,q15)
    OC(27,q16,q17) OC(28,q18,q19) OC(29,q20,q21) OC(30,q22,q23)
    OC(31,q24,q25)
#undef OC
}

extern "C" void kernel_launch(void* const* d_in, const int* in_sizes, int n_in,
                              void* d_out, int out_size, void* d_ws, size_t ws_size,
                              hipStream_t stream) {
    const float* x = (const float*)d_in[0];
    float* out   = (float*)d_out;
    int*   cnt   = (int*)d_ws;                    // 16 per-row counters (reset below)
    float* stats = (float*)d_ws + 32;             // NBLK*3 floats, offset 128 B

    hipMemsetAsync(d_ws, 0, 128, stream);         // reset barrier counters (capture-safe)
    k_fused<<<NBLK, BT, 0, stream>>>(x, cnt, stats, out);
}

// Round 11
// 257.832 us; speedup vs baseline: 1.8203x; 1.8203x over previous
//
#include <hip/hip_runtime.h>
#include <math.h>

#define ALPHA 0.99f
typedef float f4 __attribute__((ext_vector_type(4)));

constexpr int NROWS = 16;
constexpr int NS    = 1 << 21;      // samples per row
constexpr int BT    = 256;          // threads per block (4 waves)
constexpr int R     = 128;          // samples per thread
constexpr int TILE  = BT * R;       // 32768 samples per block
constexpr int BPR   = NS / TILE;    // 64 blocks per row
constexpr int NBLK  = NROWS * BPR;  // 1024 blocks = 4/CU (LDS-pinned), co-resident
constexpr int LCH   = 19;           // f4-chunks parked in LDS per thread (76 samples)
                                    // remaining 13 chunks (52 samples) in 26 named regs

constexpr double dpow(double a, long n){ double r=1.0; while(n>0){ if(n&1) r*=a; a*=a; n>>=1; } return r; }
constexpr double s2c_calc(){ double s=0,p=1; for(int t=1;t<=R;++t){ p*=0.99*0.99; s+=p; } return s; }
constexpr double csum_calc(){ double s=0,pw=1; const double f=dpow(0.99,2L*R); for(int i=0;i<BT;++i){ s+=pw; pw*=f; } return s; }

constexpr float W1  = (float)dpow(0.99, 128);   // scan hop weights alpha^(128*2^k)
constexpr float W2  = (float)dpow(0.99, 256);
constexpr float W4  = (float)dpow(0.99, 512);
constexpr float W8  = (float)dpow(0.99, 1024);
constexpr float W16 = (float)dpow(0.99, 2048);
constexpr float W32 = (float)dpow(0.99, 4096);
constexpr float ASPAN  = (float)dpow(0.99, 8192);   // 64 lanes * 128 samples (~1.6e-36, normal)
constexpr float S2C    = (float)s2c_calc();
constexpr float CCONST = (float)(s2c_calc()*csum_calc());
constexpr float L2A128 = -1.85594487f;              // 128*log2(0.99)

// RNE float->bf16 pack of two floats into one u32 (lo = a, hi = b)
static __device__ __forceinline__ unsigned pack2(float a, float b){
    unsigned ua = __builtin_bit_cast(unsigned, a);
    unsigned ub = __builtin_bit_cast(unsigned, b);
    ua += 0x7FFFu + ((ua >> 16) & 1u);
    ub += 0x7FFFu + ((ub >> 16) & 1u);
    return (ua >> 16) | (ub & 0xFFFF0000u);
}
static __device__ __forceinline__ float unlo(unsigned u){ return __builtin_bit_cast(float, u << 16); }
static __device__ __forceinline__ float unhi(unsigned u){ return __builtin_bit_cast(float, u & 0xFFFF0000u); }

// One fused kernel. R11 CHANGE vs R10 (single variable): phase-2 stores are
// PLAIN, not nontemporal. Phase-2 lanes write 512B apart, so each 16B store
// is a partial 64B line; NT (evict-first/write-through) prevented L2 line
// merging -> ~3.2x HBM write amplification (WRITE_SIZE 435-490 MB vs 134 in
// R7/R10) and serialized partial-line writes. Plain stores allocate in L2
// where the 4 consecutive chunks of each thread merge into full lines.
__global__ __launch_bounds__(BT, 4) void k_fused(const float* __restrict__ x,
                                                 int* __restrict__ cnt,     // [NROWS]
                                                 float* __restrict__ stats, // [NBLK*3]
                                                 float* __restrict__ out) {
    const int b   = blockIdx.x;
    const int row = b / BPR, jb = b % BPR;
    const int tid = threadIdx.x;
    const int lane = tid & 63, wid = tid >> 6;

    __shared__ unsigned pk_lds[2*LCH*BT];   // 38912 B: bf16-packed park, [k*BT+tid] conflict-free
    __shared__ float waveZ[4], pa[4], pb[4];
    __shared__ float sZb, sgain;

    const size_t base = (size_t)row*NS + (size_t)jb*TILE + (size_t)tid*R;
    const f4* xv = reinterpret_cast<const f4*>(x + base);

    const bool rowstart = (jb==0) && (tid==0);
    float xm1 = rowstart ? 0.0f : x[base-1];

    float z=0.f, p=1.f, S0=0.f, S1=0.f;
    float mprev = ALPHA*xm1;

#define STEP(xx, FIRST) { float m_ = ALPHA*(xx); float b_ = (FIRST) ? (xx) : (m_-mprev); \
    z = fmaf(ALPHA, z, b_); p *= ALPHA; S0 = fmaf(z,z,S0); S1 = fmaf(z,p,S1); mprev = m_; }

    // ---- phase 1a: chunks 0..18 -> LDS park (in IIR order) ----
#pragma unroll
    for (int c=0;c<LCH;++c){
        f4 v = xv[c];
        STEP(v.x, rowstart && c==0) STEP(v.y,false) STEP(v.z,false) STEP(v.w,false)
        pk_lds[(2*c  )*BT + tid] = pack2(v.x, v.y);
        pk_lds[(2*c+1)*BT + tid] = pack2(v.z, v.w);
    }

    // ---- phase 1b: chunks 19..31 -> 26 named scalar regs (in IIR order) ----
    unsigned q0,q1,q2,q3,q4,q5,q6,q7,q8,q9,q10,q11,q12,q13,
             q14,q15,q16,q17,q18,q19,q20,q21,q22,q23,q24,q25;
#define RC(c,A,B){ f4 v = xv[c]; \
    STEP(v.x,false) STEP(v.y,false) STEP(v.z,false) STEP(v.w,false) \
    A = pack2(v.x,v.y); B = pack2(v.z,v.w); }
    RC(19,q0,q1)  RC(20,q2,q3)  RC(21,q4,q5)  RC(22,q6,q7)
    RC(23,q8,q9)  RC(24,q10,q11) RC(25,q12,q13) RC(26,q14,q15)
    RC(27,q16,q17) RC(28,q18,q19) RC(29,q20,q21) RC(30,q22,q23)
    RC(31,q24,q25)
#undef RC
#undef STEP

    // ---- weighted inclusive scan of thread carries z (hop weight alpha^128) ----
    float incl = z;
    { float t1=__shfl_up(incl,1);  if(lane>=1)  incl=fmaf(W1 ,t1,incl); }
    { float t1=__shfl_up(incl,2);  if(lane>=2)  incl=fmaf(W2 ,t1,incl); }
    { float t1=__shfl_up(incl,4);  if(lane>=4)  incl=fmaf(W4 ,t1,incl); }
    { float t1=__shfl_up(incl,8);  if(lane>=8)  incl=fmaf(W8 ,t1,incl); }
    { float t1=__shfl_up(incl,16); if(lane>=16) incl=fmaf(W16,t1,incl); }
    { float t1=__shfl_up(incl,32); if(lane>=32) incl=fmaf(W32,t1,incl); }

    if (lane==63) waveZ[wid]=incl;
    __syncthreads();

    float P=0.f;
    for (int u=0;u<wid;++u) P=fmaf(ASPAN,P,waveZ[u]);   // state entering this wave

    float excl=__shfl_up(incl,1); if(lane==0) excl=0.f;
    float wl = exp2f((float)lane * L2A128);             // alpha^(128*lane)
    float E  = fmaf(wl,P,excl);                         // state entering this thread

    // per-thread contribution, quadratic in block-incoming state Y
    float ai = fmaf(S2C*E,E, fmaf(2.0f*S1,E,S0));
    float Qi = exp2f((float)tid * L2A128);              // alpha^(128*tid) (underflow->0 ok)
    float bi = 2.0f*Qi*fmaf(S2C,E,S1);

    if (tid==BT-1) sZb = fmaf(ASPAN,P,incl);            // block zero-state output

    for (int d=32; d; d>>=1){ ai+=__shfl_xor(ai,d); bi+=__shfl_xor(bi,d); }
    if (lane==0){ pa[wid]=ai; pb[wid]=bi; }
    __syncthreads();

    // ---- publish stats + per-row arrive/spin barrier (R5-proven pattern) ----
    if (tid==0){
        float A = pa[0]+pa[1]+pa[2]+pa[3];
        float B = pb[0]+pb[1]+pb[2]+pb[3];
        __hip_atomic_store(&stats[b*3+0], A,   __ATOMIC_RELAXED, __HIP_MEMORY_SCOPE_AGENT);
        __hip_atomic_store(&stats[b*3+1], B,   __ATOMIC_RELAXED, __HIP_MEMORY_SCOPE_AGENT);
        __hip_atomic_store(&stats[b*3+2], sZb, __ATOMIC_RELAXED, __HIP_MEMORY_SCOPE_AGENT);
        __threadfence();
        atomicAdd(&cnt[row], 1);
        while (__hip_atomic_load(&cnt[row], __ATOMIC_ACQUIRE, __HIP_MEMORY_SCOPE_AGENT) < BPR)
            __builtin_amdgcn_s_sleep(8);
    }
    __syncthreads();

    // ---- row gain: wave 0 reduces its row's 64 block-stats (deterministic) ----
    if (tid < 64){
        const float* st = &stats[((size_t)row*BPR + lane)*3];
        float a2 = __hip_atomic_load(&st[0], __ATOMIC_RELAXED, __HIP_MEMORY_SCOPE_AGENT);
        float b2 = __hip_atomic_load(&st[1], __ATOMIC_RELAXED, __HIP_MEMORY_SCOPE_AGENT);
        float zl = __hip_atomic_load(&st[2], __ATOMIC_RELAXED, __HIP_MEMORY_SCOPE_AGENT);
        float zp = __shfl_up(zl,1); if(lane==0) zp=0.f; // Y_in(block j) = Z_{j-1}
        float s = fmaf(CCONST, zp*zp, fmaf(b2,zp,a2));
        for (int d=32; d; d>>=1) s += __shfl_xor(s,d);
        if (tid==0){
            float ms   = s * (1.0f/(float)NS);
            float lufs = -0.691f + 10.0f*log10f(ms + 1e-8f);
            float gdb  = fminf(fmaxf(-23.0f-lufs,-30.0f),30.0f);
            sgain = exp2f(gdb*0.1660964047f);           // 10^(gdb/20)
        }
    }
    __syncthreads();
    const float g = sgain;

    // ---- phase 2: unpack parked bf16 (LDS + regs), scale, PLAIN-store out ----
    f4* ov = reinterpret_cast<f4*>(out + base);
#pragma unroll
    for (int c=0;c<LCH;++c){
        unsigned a_ = pk_lds[(2*c  )*BT + tid];
        unsigned b_ = pk_lds[(2*c+1)*BT + tid];
        f4 w;
        w.x = unlo(a_)*g; w.y = unhi(a_)*g;
        w.z = unlo(b_)*g; w.w = unhi(b_)*g;
        ov[c] = w;
    }
#define OC(c,A,B){ f4 w; \
    w.x = unlo(A)*g; w.y = unhi(A)*g; w.z = unlo(B)*g; w.w = unhi(B)*g; \
    ov[(c)] = w; }
    OC(19,q0,q1)  OC(20,q2,q3)  OC(21,q4,q5)  OC(22,q6,q7)
    OC(23,q8,q9)  OC(24,q10,q11) OC(25,q12,q13) OC(26,q14,q15)
    OC(27,q16,q17) OC(28,q18,q19) OC(29,q20,q21) OC(30,q22,q23)
    OC(31,q24,q25)
#undef OC
}

extern "C" void kernel_launch(void* const* d_in, const int* in_sizes, int n_in,
                              void* d_out, int out_size, void* d_ws, size_t ws_size,
                              hipStream_t stream) {
    const float* x = (const float*)d_in[0];
    float* out   = (float*)d_out;
    int*   cnt   = (int*)d_ws;                    // 16 per-row counters (reset below)
    float* stats = (float*)d_ws + 32;             // NBLK*3 floats, offset 128 B

    hipMemsetAsync(d_ws, 0, 128, stream);         // reset barrier counters (capture-safe)
    k_fused<<<NBLK, BT, 0, stream>>>(x, cnt, stats, out);
}

// Round 12
// 65.748 us; speedup vs baseline: 7.1384x; 3.9215x over previous
//
#include <hip/hip_runtime.h>
#include <math.h>

#define ALPHA 0.99f

typedef float f4 __attribute__((ext_vector_type(4)));  // native vector, OK for nontemporal builtins

constexpr int R   = 16;            // samples per thread
constexpr int BT  = 256;           // threads per block
constexpr int TILE = R * BT;       // 4096 samples per block
constexpr int NROWS = 16;
constexpr int NS  = 1 << 21;       // 2097152 samples per row
constexpr int BPR = NS / TILE;     // 512 blocks per row
constexpr int NBLOCKS = NROWS * BPR; // 8192

// exact double-precision powers of alpha at compile time
constexpr double dpow(double a, long n) {
    double r = 1.0;
    while (n > 0) { if (n & 1) r *= a; a *= a; n >>= 1; }
    return r;
}
constexpr double s2c_calc() {       // sum_{t=1..R} alpha^{2t}
    double s = 0.0, p = 1.0;
    for (int t = 1; t <= R; ++t) { p *= 0.99 * 0.99; s += p; }
    return s;
}
constexpr double csum_calc() {      // sum_{i=0..BT-1} alpha^{2*R*i}
    double s = 0.0;
    for (int i = 0; i < BT; ++i) s += dpow(0.99, 32L * i);
    return s;
}

constexpr float W1    = (float)dpow(0.99, 16);    // scan weights: alpha^(16*s)
constexpr float W2    = (float)dpow(0.99, 32);
constexpr float W4    = (float)dpow(0.99, 64);
constexpr float W8    = (float)dpow(0.99, 128);
constexpr float W16   = (float)dpow(0.99, 256);
constexpr float W32   = (float)dpow(0.99, 512);
constexpr float A1024 = (float)dpow(0.99, 1024);  // wave span decay
constexpr float A2048 = (float)dpow(0.99, 2048);
constexpr float A3072 = (float)dpow(0.99, 3072);
constexpr float S2C   = (float)s2c_calc();
constexpr float CCONST = (float)(s2c_calc() * csum_calc());
constexpr float L2A16 = -0.231993109f;            // 16*log2(0.99)

// K1: per-block (A, B, Z): BlockSumSq(Y_in) = A + B*Y_in + CCONST*Y_in^2,
//     Z = zero-state filter output at end of block tile.
__global__ __launch_bounds__(256) void k_scan(const float* __restrict__ x,
                                              float* __restrict__ blk) {
    const int b   = blockIdx.x;
    const int row = b / BPR;
    const int jb  = b % BPR;
    const int tid = threadIdx.x;
    const int lane = tid & 63, wid = tid >> 6;

    const size_t base = (size_t)row * NS + (size_t)jb * TILE + (size_t)tid * R;
    const float4* xp = reinterpret_cast<const float4*>(x + base);
    float4 v0 = xp[0], v1 = xp[1], v2 = xp[2], v3 = xp[3];

    const bool rowstart = (jb == 0) && (tid == 0);
    float xm1 = rowstart ? 0.0f : x[base - 1];

    float xs[16] = { v0.x, v0.y, v0.z, v0.w,
                     v1.x, v1.y, v1.z, v1.w,
                     v2.x, v2.y, v2.z, v2.w,
                     v3.x, v3.y, v3.z, v3.w };

    // serial zero-state pass over 16 samples
    float mprev = ALPHA * xm1;
    float z = 0.0f, p = 1.0f, S0 = 0.0f, S1 = 0.0f;
#pragma unroll
    for (int t = 0; t < 16; ++t) {
        float m  = ALPHA * xs[t];
        float bb = m - mprev;
        if (rowstart && t == 0) bb = xs[0];   // y[0] = x[0] exactly
        z = fmaf(ALPHA, z, bb);               // z_t = a*z_{t-1} + b_t
        p *= ALPHA;                           // p = alpha^t
        S0 = fmaf(z, z, S0);
        S1 = fmaf(z, p, S1);
        mprev = m;
    }

    // weighted inclusive scan of per-thread carries z (weight alpha^16 per hop)
    float incl = z;
    { float t1 = __shfl_up(incl, 1);  if (lane >= 1)  incl = fmaf(W1,  t1, incl); }
    { float t1 = __shfl_up(incl, 2);  if (lane >= 2)  incl = fmaf(W2,  t1, incl); }
    { float t1 = __shfl_up(incl, 4);  if (lane >= 4)  incl = fmaf(W4,  t1, incl); }
    { float t1 = __shfl_up(incl, 8);  if (lane >= 8)  incl = fmaf(W8,  t1, incl); }
    { float t1 = __shfl_up(incl, 16); if (lane >= 16) incl = fmaf(W16, t1, incl); }
    { float t1 = __shfl_up(incl, 32); if (lane >= 32) incl = fmaf(W32, t1, incl); }

    __shared__ float waveZ[4];
    __shared__ float pa[4], pb[4];
    __shared__ float sZb;
    if (lane == 63) waveZ[wid] = incl;
    __syncthreads();

    // state entering this wave (block zero-state)
    float P = 0.0f;
    for (int u = 0; u < wid; ++u) P = fmaf(A1024, P, waveZ[u]);

    // exclusive carry entering this thread
    float excl = __shfl_up(incl, 1);
    if (lane == 0) excl = 0.0f;
    float wl = exp2f((float)lane * L2A16);     // alpha^(16*lane)
    float E  = fmaf(wl, P, excl);

    // thread contribution, expanded in block-incoming state Y:
    // S0 + 2*S1*y_in + S2C*y_in^2, y_in = E + Q*Y
    float ai = fmaf(S2C * E, E, fmaf(2.0f * S1, E, S0));
    float qw = (wid == 0) ? 1.0f : (wid == 1) ? A1024 : (wid == 2) ? A2048 : A3072;
    float Qi = wl * qw;                        // alpha^(16*tid)
    float bi = 2.0f * Qi * fmaf(S2C, E, S1);

    // block zero-state output
    if (tid == 255) sZb = fmaf(A1024, P, incl);

    // reduce ai, bi across wave then block
    for (int d = 32; d; d >>= 1) { ai += __shfl_xor(ai, d); bi += __shfl_xor(bi, d); }
    if (lane == 0) { pa[wid] = ai; pb[wid] = bi; }
    __syncthreads();

    if (tid == 0) {
        float A = pa[0] + pa[1] + pa[2] + pa[3];
        float B = pb[0] + pb[1] + pb[2] + pb[3];
        blk[(size_t)b * 3 + 0] = A;
        blk[(size_t)b * 3 + 1] = B;
        blk[(size_t)b * 3 + 2] = sZb;
    }
}

// K2 (fused gain+scale): each block covers exactly one 4096-float4 segment of
// one row (128 blocks per row). It first redundantly reduces its row's 512
// block-stats (L2-resident, ~6 KB) to the row gain, then scales its segment.
// x read with NORMAL loads; out written with NT stores (lane-contiguous ->
// full-line bursts, no write amplification).
__global__ __launch_bounds__(256) void k_scale(const float* __restrict__ x,
                                               const float* __restrict__ blk,
                                               float* __restrict__ out) {
    const int row = blockIdx.x >> 7;     // 128 blocks per row
    const int seg = blockIdx.x & 127;
    const int tid = threadIdx.x;
    const int lane = tid & 63, wid = tid >> 6;

    // ---- row gain (redundant per block, deterministic) ----
    float s = 0.0f;
#pragma unroll
    for (int k = 0; k < 2; ++k) {
        int j = tid + k * BT;                       // 0..511
        size_t idx = (size_t)row * BPR + j;
        float A  = blk[idx * 3 + 0];
        float B  = blk[idx * 3 + 1];
        float Zp = (j == 0) ? 0.0f : blk[idx * 3 - 1];  // (idx-1)*3+2
        s += fmaf(CCONST, Zp * Zp, fmaf(B, Zp, A));
    }
    for (int d = 32; d; d >>= 1) s += __shfl_xor(s, d);
    __shared__ float ps[4];
    __shared__ float sgain;
    if (lane == 0) ps[wid] = s;
    __syncthreads();
    if (tid == 0) {
        float total = ps[0] + ps[1] + ps[2] + ps[3];
        float ms   = total * (1.0f / (float)NS);
        float lufs = -0.691f + 10.0f * log10f(ms + 1e-8f);
        float gdb  = fminf(fmaxf(-23.0f - lufs, -30.0f), 30.0f);
        sgain = exp2f(gdb * 0.1660964047f);         // 10^(gdb/20)
    }
    __syncthreads();
    const float g = sgain;

    // ---- scale this block's segment ----
    const size_t base4 = (size_t)row * (NS / 4) + (size_t)seg * 4096;
    const f4* xi = reinterpret_cast<const f4*>(x) + base4;
    f4* oo = reinterpret_cast<f4*>(out) + base4;
#pragma unroll 4
    for (int k = 0; k < 16; ++k) {
        int i = k * BT + tid;
        f4 v = xi[i];                        // normal load (L3 if resident)
        v *= g;
        __builtin_nontemporal_store(v, oo + i);  // lane-contiguous NT store
    }
}

extern "C" void kernel_launch(void* const* d_in, const int* in_sizes, int n_in,
                              void* d_out, int out_size, void* d_ws, size_t ws_size,
                              hipStream_t stream) {
    const float* x = (const float*)d_in[0];
    float* out = (float*)d_out;
    float* blk = (float*)d_ws;                 // NBLOCKS*3 floats

    k_scan<<<NBLOCKS, BT, 0, stream>>>(x, blk);
    k_scale<<<2048, BT, 0, stream>>>(x, blk, out);
}